// Round 2
// baseline (411.166 us; speedup 1.0000x reference)
//
#include <hip/hip_runtime.h>

// y[n] = x[n] + ALPHA * y[n-1], zero init, per row. 64 rows x 960000 fp32.
// Chunked parallel scan with warm-up lookback. alpha^192 ~ 2.6e-14 => 192-sample
// lookback makes chunks independent to far below fp32 noise (harness absmax
// slack is ~0.03; carry error here is ~1e-13).
//
// v3: window doubled to 8192 (G=8 float4 groups/wave, 4 waves), LOOK shrunk
// 256->192 => CHUNK=8000, 120 chunks/row exact. Lookback re-read overhead
// 6.7%->2.4%; block count halves to 7680. Output uses nontemporal stores
// (write-once stream; keep L2 for the input).
// Layout: lane-interleaved float4 -- lane l owns elements [4l,4l+4) of each
// 256-element group; fully coalesced 1KB-per-wave loads/stores.

#define ALPHA 0.85f

constexpr int ROW    = 960000;
constexpr int BT     = 256;            // 4 waves per block
constexpr int WAVES  = BT / 64;
constexpr int G      = 8;              // float4 groups per wave
constexpr int GELEM  = 256;            // elements per group (64 lanes * 4)
constexpr int WELEM  = G * GELEM;      // 2048 elements per wave
constexpr int TOT    = WAVES * WELEM;  // 8192-element window
constexpr int LOOK   = 192;            // warm-up lookback (48 lanes * 4)
constexpr int LOOKL  = LOOK / 4;       // 48: lanes of wave0/group0 in lookback
constexpr int CHUNK  = TOT - LOOK;     // 8000 outputs per block
constexpr int CHUNKS = ROW / CHUNK;    // 120 (exact: 960000 = 120*8000)

// alpha^n at compile time (double accumulate, cast to float).
constexpr float apow(int n) {
    double r = 1.0;
    for (int i = 0; i < n; ++i) r *= 0.85;
    return (float)r;
}

constexpr float A1    = apow(1);
constexpr float A2    = apow(2);
constexpr float A3    = apow(3);
constexpr float A4    = apow(4);
constexpr float A8    = apow(8);
constexpr float A16   = apow(16);
constexpr float A32   = apow(32);
constexpr float A64   = apow(64);
constexpr float A128  = apow(128);
constexpr float A256  = apow(256);     // ~8.7e-19: cross-group carry weight
constexpr float AW    = apow(WELEM);   // alpha^2048: underflows to 0.0f -- fine
constexpr float LOG2_A4 = -0.9378610145f;  // 4 * log2(0.85)

typedef float f4 __attribute__((ext_vector_type(4)));

__global__ __launch_bounds__(BT) void deemph_kernel(const float* __restrict__ x,
                                                    float* __restrict__ y) {
    const int blk  = blockIdx.x;
    const int r    = blk / CHUNKS;
    const int c    = blk - r * CHUNKS;
    const int t    = threadIdx.x;
    const int lane = t & 63;
    const int wave = t >> 6;

    // window element 0 = chunk start - LOOK
    const long long winbase = (long long)r * ROW + (long long)c * CHUNK - LOOK;
    const int woff0 = wave * WELEM + 4 * lane;   // window offset of lane's group-0 quad

    // ---- coalesced loads + in-lane serial scan of each 4-elem quad.
    // Lookback region = window [0,192) = wave0/group0 lanes<48. For c==0 that
    // region is pre-row: must be zeros and the load must not be issued (OOB at r==0).
    float v0[G], v1[G], v2[G], v3[G], acc[G];
    #pragma unroll
    for (int g = 0; g < G; ++g) {
        f4 q;
        const bool zero = (c == 0) && (wave == 0) && (g == 0) && (lane < LOOKL);
        if (zero) {
            q = (f4){0.f, 0.f, 0.f, 0.f};
        } else {
            q = *(const f4*)(x + winbase + woff0 + g * GELEM);
        }
        float s;
        s = q.x;             v0[g] = s;
        s = q.y + ALPHA * s; v1[g] = s;
        s = q.z + ALPHA * s; v2[g] = s;
        s = q.w + ALPHA * s; v3[g] = s;
        acc[g] = s;          // lane segment sum (state after 4 elems, zero-in)
    }

    // ---- weighted Kogge-Stone inclusive scan across lanes, per group.
    // 8 independent 6-step chains -> deep ILP for shuffle latency.
    #pragma unroll
    for (int g = 0; g < G; ++g) {
        float up;
        up = __shfl_up(acc[g], 1, 64);  if (lane >= 1)  acc[g] += A4   * up;
        up = __shfl_up(acc[g], 2, 64);  if (lane >= 2)  acc[g] += A8   * up;
        up = __shfl_up(acc[g], 4, 64);  if (lane >= 4)  acc[g] += A16  * up;
        up = __shfl_up(acc[g], 8, 64);  if (lane >= 8)  acc[g] += A32  * up;
        up = __shfl_up(acc[g], 16, 64); if (lane >= 16) acc[g] += A64  * up;
        up = __shfl_up(acc[g], 32, 64); if (lane >= 32) acc[g] += A128 * up;
    }

    // ---- group totals (state after 256 elems, zero-in) + exclusive per-lane
    float T[G], ex[G];
    #pragma unroll
    for (int g = 0; g < G; ++g) {
        T[g] = __shfl(acc[g], 63, 64);
        float e = __shfl_up(acc[g], 1, 64);
        ex[g] = (lane == 0) ? 0.0f : e;
    }

    // wave total: chain the G group totals
    float WT = T[0];
    #pragma unroll
    for (int g = 1; g < G; ++g) WT = T[g] + A256 * WT;

    // ---- cross-wave combine (4 waves); AW==0 so only the previous wave matters,
    // but keep the generic chain (compile-time constant folds it).
    __shared__ float wsum[WAVES];
    if (lane == 0) wsum[wave] = WT;
    __syncthreads();
    float W = 0.0f;                          // state at start of this wave
    #pragma unroll
    for (int w2 = 0; w2 < WAVES - 1; ++w2)
        if (w2 < wave) W = wsum[w2] + AW * W;

    // state at start of each group
    float S[G];
    S[0] = W;
    #pragma unroll
    for (int g = 1; g < G; ++g) S[g] = T[g-1] + A256 * S[g-1];

    // propagate group-start state through 4*lane elements
    const float al4 = exp2f((float)lane * LOG2_A4);

    // ---- apply prefix + coalesced nontemporal stores.
    // Window [0,192) (wave0/g0 lanes<48) is lookback: belongs to previous chunk,
    // never stored. Lanes >=48 of that group DO store (chunk outputs [0,64)).
    #pragma unroll
    for (int g = 0; g < G; ++g) {
        const bool skip = (wave == 0) && (g == 0) && (lane < LOOKL);
        const float P = ex[g] + al4 * S[g];  // state just before this lane's quad
        f4 o;
        o.x = v0[g] + A1 * P;
        o.y = v1[g] + A2 * P;
        o.z = v2[g] + A3 * P;
        o.w = v3[g] + A4 * P;
        if (!skip) {
            __builtin_nontemporal_store(o, (f4*)(y + winbase + woff0 + g * GELEM));
        }
    }
}

extern "C" void kernel_launch(void* const* d_in, const int* in_sizes, int n_in,
                              void* d_out, int out_size, void* d_ws, size_t ws_size,
                              hipStream_t stream) {
    const float* x = (const float*)d_in[0];
    float* y = (float*)d_out;
    const int nrows = in_sizes[0] / ROW;     // 64
    deemph_kernel<<<dim3(nrows * CHUNKS), dim3(BT), 0, stream>>>(x, y);
}

// Round 3
// 399.607 us; speedup vs baseline: 1.0289x; 1.0289x over previous
//
#include <hip/hip_runtime.h>

// y[n] = x[n] + ALPHA * y[n-1], zero init, per row. 64 rows x 960000 fp32.
// Chunked parallel scan with warm-up lookback. alpha^96 ~ 1.7e-7 => 96-sample
// lookback makes chunks independent to ~1e-6 absolute error (harness absmax
// slack ~0.03).
//
// v4: v2 geometry (G=4, 4096-element window -- stays under the 64-VGPR
// occupancy cliff that v3's G=8 crossed, 8 waves/SIMD) with v3's lookback
// shrink applied at this window size: LOOK=96 -> CHUNK=4000, 240 chunks/row
// exact. Lookback re-read overhead 6.7% -> 2.4%. Plain stores (v3's
// nontemporal rider reverted -- untested and possibly harmful).
// Layout: lane-interleaved float4 -- lane l owns elements [4l,4l+4) of each
// 256-element group; fully coalesced 1KB-per-wave loads/stores.

#define ALPHA 0.85f

constexpr int ROW    = 960000;
constexpr int BT     = 256;            // 4 waves per block
constexpr int WAVES  = BT / 64;
constexpr int G      = 4;              // float4 groups per wave
constexpr int GELEM  = 256;            // elements per group (64 lanes * 4)
constexpr int WELEM  = G * GELEM;      // 1024 elements per wave
constexpr int TOT    = WAVES * WELEM;  // 4096-element window
constexpr int LOOK   = 96;             // warm-up lookback (24 lanes * 4)
constexpr int LOOKL  = LOOK / 4;       // 24: lanes of wave0/group0 in lookback
constexpr int CHUNK  = TOT - LOOK;     // 4000 outputs per block
constexpr int CHUNKS = ROW / CHUNK;    // 240 (exact: 960000 = 240*4000)

// alpha^n at compile time (double accumulate, cast to float).
constexpr float apow(int n) {
    double r = 1.0;
    for (int i = 0; i < n; ++i) r *= 0.85;
    return (float)r;
}

constexpr float A1    = apow(1);
constexpr float A2    = apow(2);
constexpr float A3    = apow(3);
constexpr float A4    = apow(4);
constexpr float A8    = apow(8);
constexpr float A16   = apow(16);
constexpr float A32   = apow(32);
constexpr float A64   = apow(64);
constexpr float A128  = apow(128);
constexpr float A256  = apow(256);     // ~8.7e-19: cross-group carry weight
constexpr float AW    = apow(WELEM);   // alpha^1024: underflows to 0.0f -- fine
constexpr float LOG2_A4 = -0.9378610145f;  // 4 * log2(0.85)

typedef float f4 __attribute__((ext_vector_type(4)));

__global__ __launch_bounds__(BT) void deemph_kernel(const float* __restrict__ x,
                                                    float* __restrict__ y) {
    const int blk  = blockIdx.x;
    const int r    = blk / CHUNKS;
    const int c    = blk - r * CHUNKS;
    const int t    = threadIdx.x;
    const int lane = t & 63;
    const int wave = t >> 6;

    // window element 0 = chunk start - LOOK
    const long long winbase = (long long)r * ROW + (long long)c * CHUNK - LOOK;
    const int woff0 = wave * WELEM + 4 * lane;   // window offset of lane's group-0 quad

    // ---- coalesced loads + in-lane serial scan of each 4-elem quad.
    // Lookback region = window [0,96) = wave0/group0 lanes<24. For c==0 that
    // region is pre-row: must be zeros and the load must not be issued (OOB at r==0).
    float v0[G], v1[G], v2[G], v3[G], acc[G];
    #pragma unroll
    for (int g = 0; g < G; ++g) {
        f4 q;
        const bool zero = (c == 0) && (wave == 0) && (g == 0) && (lane < LOOKL);
        if (zero) {
            q = (f4){0.f, 0.f, 0.f, 0.f};
        } else {
            q = *(const f4*)(x + winbase + woff0 + g * GELEM);
        }
        float s;
        s = q.x;             v0[g] = s;
        s = q.y + ALPHA * s; v1[g] = s;
        s = q.z + ALPHA * s; v2[g] = s;
        s = q.w + ALPHA * s; v3[g] = s;
        acc[g] = s;          // lane segment sum (state after 4 elems, zero-in)
    }

    // ---- weighted Kogge-Stone inclusive scan across lanes, per group.
    // 4 independent 6-step chains -> ILP for shuffle latency.
    #pragma unroll
    for (int g = 0; g < G; ++g) {
        float up;
        up = __shfl_up(acc[g], 1, 64);  if (lane >= 1)  acc[g] += A4   * up;
        up = __shfl_up(acc[g], 2, 64);  if (lane >= 2)  acc[g] += A8   * up;
        up = __shfl_up(acc[g], 4, 64);  if (lane >= 4)  acc[g] += A16  * up;
        up = __shfl_up(acc[g], 8, 64);  if (lane >= 8)  acc[g] += A32  * up;
        up = __shfl_up(acc[g], 16, 64); if (lane >= 16) acc[g] += A64  * up;
        up = __shfl_up(acc[g], 32, 64); if (lane >= 32) acc[g] += A128 * up;
    }

    // ---- group totals (state after 256 elems, zero-in) + exclusive per-lane
    float T[G], ex[G];
    #pragma unroll
    for (int g = 0; g < G; ++g) {
        T[g] = __shfl(acc[g], 63, 64);
        float e = __shfl_up(acc[g], 1, 64);
        ex[g] = (lane == 0) ? 0.0f : e;
    }

    // wave total: chain the G group totals
    float WT = T[0];
    #pragma unroll
    for (int g = 1; g < G; ++g) WT = T[g] + A256 * WT;

    // ---- cross-wave combine (4 waves); AW==0 so only the previous wave's
    // total matters, but keep the generic chain (constant-folds).
    __shared__ float wsum[WAVES];
    if (lane == 0) wsum[wave] = WT;
    __syncthreads();
    float W = 0.0f;                          // state at start of this wave
    #pragma unroll
    for (int w2 = 0; w2 < WAVES - 1; ++w2)
        if (w2 < wave) W = wsum[w2] + AW * W;

    // state at start of each group
    float S[G];
    S[0] = W;
    #pragma unroll
    for (int g = 1; g < G; ++g) S[g] = T[g-1] + A256 * S[g-1];

    // propagate group-start state through 4*lane elements
    const float al4 = exp2f((float)lane * LOG2_A4);

    // ---- apply prefix + coalesced stores.
    // Window [0,96) (wave0/g0 lanes<24) is lookback: belongs to previous chunk,
    // never stored. Lanes >=24 of that group DO store (chunk outputs [0,160)).
    #pragma unroll
    for (int g = 0; g < G; ++g) {
        const bool skip = (wave == 0) && (g == 0) && (lane < LOOKL);
        const float P = ex[g] + al4 * S[g];  // state just before this lane's quad
        f4 o;
        o.x = v0[g] + A1 * P;
        o.y = v1[g] + A2 * P;
        o.z = v2[g] + A3 * P;
        o.w = v3[g] + A4 * P;
        if (!skip) {
            *(f4*)(y + winbase + woff0 + g * GELEM) = o;
        }
    }
}

extern "C" void kernel_launch(void* const* d_in, const int* in_sizes, int n_in,
                              void* d_out, int out_size, void* d_ws, size_t ws_size,
                              hipStream_t stream) {
    const float* x = (const float*)d_in[0];
    float* y = (float*)d_out;
    const int nrows = in_sizes[0] / ROW;     // 64
    deemph_kernel<<<dim3(nrows * CHUNKS), dim3(BT), 0, stream>>>(x, y);
}